// Round 1
// 424.909 us; speedup vs baseline: 1.3157x; 1.3157x over previous
//
#include <hip/hip_runtime.h>

// CausalSelfAttention: B=2, S=2048, H=2048, NH=16, HD=128. f32 in/out, bf16 MFMA inside.
// R9 = R8 + attn latency attack (attn was 230us, MfmaUtil 8.9% -> latency-bound):
//   (a) XCD-aware block remap: each XCD gets 4 consecutive bh -> K/V working set
//       per XCD drops 32MB -> 4MB (~L2), LLC-latency hits become L2 hits.
//   (b) Register prefetch: K tile double-buffered (kt+1 prefetched during kt),
//       V tile issued at top of iteration, consumed after QK+exp (~150cy later).
//       Unroll-by-2 with named buffers (static indexing, no scratch).
//   (c) V fragment-pack widened: [kt][ctp:4][qv:4][lv:16][8] so V loads are
//       4x dwordx4 instead of 8x dwordx2.
//   (d) wave-role rotation by (u>>5)&3 so each SIMD gets a mix of strip lengths.
// Attention core unchanged: S^T = K*Q^T operand swap, C-regs are the A-fragment
// of mfma_16x16x16 for P*V, no LDS, no barriers.

using bf16x8 = __attribute__((ext_vector_type(8))) short;
using bf16x4 = __attribute__((ext_vector_type(4))) short;
using f32x4  = __attribute__((ext_vector_type(4))) float;

#define S_LEN 2048
#define NHEAD 16
#define HDIM  128
#define HID   2048

__device__ __forceinline__ unsigned short f2bf(float f) {
    unsigned int u = __float_as_uint(f);
    u += 0x7fffu + ((u >> 16) & 1u);   // round-to-nearest-even
    return (unsigned short)(u >> 16);
}
__device__ __forceinline__ void gl2lds16(const void* g, void* l) {
    __builtin_amdgcn_global_load_lds(
        (const __attribute__((address_space(1))) void*)g,
        (__attribute__((address_space(3))) void*)l, 16, 0, 0);
}

// 16x16x16 bf16 MFMA, device-guarded (host pass must not reference the builtin).
__device__ __forceinline__ f32x4 pv_mfma(bf16x4 a, bf16x4 b, f32x4 c) {
#if defined(__HIP_DEVICE_COMPILE__)
#if __has_builtin(__builtin_amdgcn_mfma_f32_16x16x16bf16_1k)
    return __builtin_amdgcn_mfma_f32_16x16x16bf16_1k(a, b, c, 0, 0, 0);
#else
    asm("v_mfma_f32_16x16x16_bf16 %0, %1, %2, %0" : "+v"(c) : "v"(a), "v"(b));
    return c;
#endif
#else
    (void)a; (void)b;
    return c;
#endif
}

// ---------------------------------------------------------------- convert x: f32 -> bf16
__global__ void convert_x(const float* __restrict__ x, unsigned short* __restrict__ xb) {
    int i = (blockIdx.x * 256 + threadIdx.x) * 4;
    float4 v = *(const float4*)(x + i);
    ushort4 o;
    o.x = f2bf(v.x); o.y = f2bf(v.y); o.z = f2bf(v.z); o.w = f2bf(v.w);
    *(ushort4*)(xb + i) = o;
}

// ------------------------------------------------- convert+transpose weights: f32 -> bf16^T
__global__ void convert_wt(const float* __restrict__ w0, const float* __restrict__ w1,
                           const float* __restrict__ w2, const float* __restrict__ w3,
                           unsigned short* __restrict__ t0, unsigned short* __restrict__ t1,
                           unsigned short* __restrict__ t2, unsigned short* __restrict__ t3) {
    __shared__ float tile[64][65];
    int z = blockIdx.z;
    const float* src = (z == 0) ? w0 : (z == 1) ? w1 : (z == 2) ? w2 : w3;
    unsigned short* dst = (z == 0) ? t0 : (z == 1) ? t1 : (z == 2) ? t2 : t3;
    int r0 = blockIdx.y * 64, c0 = blockIdx.x * 64;
    int t = threadIdx.x;
    for (int i = t; i < 64 * 64; i += 256) {
        int r = i >> 6, c = i & 63;
        tile[r][c] = src[(size_t)(r0 + r) * HID + c0 + c];
    }
    __syncthreads();
    for (int i = t; i < 64 * 64; i += 256) {
        int r = i & 63, c = i >> 6;
        dst[(size_t)(c0 + c) * HID + r0 + r] = f2bf(tile[r][c]);
    }
}

// ---------------------------------------------------------------- GEMM (m97 pattern)
// C[4096][2048] = A @ Bt^T + bias; A,Bt bf16, fp32 acc.
// MODE 0: f32 row-major to Cf (out-proj -> d_out)
// MODE 1: z=0 (Q): bf16 head-split [b,h,s,d]
//         z=1 (K): fragment-packed Kp[bh][kt16][kk4][quad][l15][8]  (key=kt*16+l15, d=kk*32+quad*8+e)
//         z=2 (V): fragment-packed Vp[bh][kt16][ctp4][quad][l15][8] (key=kt*16+quad*4+e, d=ctp*32+(ee>>2)*16+l15)
template <int MODE>
__launch_bounds__(256, 2)
__global__ void gemm_bt(const unsigned short* __restrict__ A,
                        const unsigned short* __restrict__ Bt0,
                        const unsigned short* __restrict__ Bt1,
                        const unsigned short* __restrict__ Bt2,
                        const float* __restrict__ bias0,
                        const float* __restrict__ bias1,
                        const float* __restrict__ bias2,
                        unsigned short* __restrict__ C0,
                        unsigned short* __restrict__ C1,
                        unsigned short* __restrict__ C2,
                        float* __restrict__ Cf) {
    __shared__ __align__(16) unsigned short As[128 * 32];
    __shared__ __align__(16) unsigned short Bs[128 * 32];

    const unsigned short* Bt = Bt0;
    const float* bias = bias0;
    unsigned short* C = C0;
    if (MODE == 1) {
        int z = blockIdx.z;
        if (z == 1) { Bt = Bt1; bias = bias1; C = C1; }
        else if (z == 2) { Bt = Bt2; bias = bias2; C = C2; }
    }

    const int K = HID;
    int m0 = blockIdx.y * 128;
    int n0 = blockIdx.x * 128;
    int tid = threadIdx.x;
    int lane = tid & 63;
    int w = tid >> 6;
    int wr = w >> 1, wc = w & 1;
    int l15 = lane & 15;
    int quad = lane >> 4;

    f32x4 acc[4][4];
#pragma unroll
    for (int i = 0; i < 4; ++i)
#pragma unroll
        for (int j = 0; j < 4; ++j) acc[i][j] = (f32x4){0.f, 0.f, 0.f, 0.f};

    int srow = w * 16 + (lane >> 2);
    int scol = (lane & 3) * 8;
    const unsigned short* gA = A + (size_t)(m0 + srow) * K + scol;
    const unsigned short* gB = Bt + (size_t)(n0 + srow) * K + scol;
    unsigned short* lA = &As[w * 512];
    unsigned short* lB = &Bs[w * 512];

    for (int k0 = 0; k0 < K; k0 += 32) {
        gl2lds16(gA + k0,                  lA);
        gl2lds16(gA + (size_t)64 * K + k0, lA + 2048);
        gl2lds16(gB + k0,                  lB);
        gl2lds16(gB + (size_t)64 * K + k0, lB + 2048);
        __syncthreads();

        bf16x8 av[4], bv[4];
        int q8 = quad * 8;
#pragma unroll
        for (int i = 0; i < 4; ++i) av[i] = *(const bf16x8*)&As[(wr * 64 + i * 16 + l15) * 32 + q8];
#pragma unroll
        for (int j = 0; j < 4; ++j) bv[j] = *(const bf16x8*)&Bs[(wc * 64 + j * 16 + l15) * 32 + q8];
#pragma unroll
        for (int i = 0; i < 4; ++i)
#pragma unroll
            for (int j = 0; j < 4; ++j)
                acc[i][j] = __builtin_amdgcn_mfma_f32_16x16x32_bf16(av[i], bv[j], acc[i][j], 0, 0, 0);
        __syncthreads();
    }

    int zz = (MODE == 1) ? blockIdx.z : 0;
#pragma unroll
    for (int j = 0; j < 4; ++j) {
        int n = n0 + wc * 64 + j * 16 + l15;
        float bn = bias[n];
#pragma unroll
        for (int i = 0; i < 4; ++i) {
            int mb = m0 + wr * 64 + i * 16 + quad * 4;   // base row, regs = mb..mb+3
            if (MODE == 1 && zz == 2) {
                // V-pack: 4 regs = 4 consecutive keys (e=0..3) -> one ushort4.
                // Layout [bh][kt:128][ctp:4][qv:4][lv:16][ee:8], ee=(ct&1)*4+e.
                int b = mb >> 11, s = mb & 2047, h = n >> 7, d = n & 127;
                int kt = s >> 4, qv = (s >> 2) & 3, ct = d >> 4, lv = d & 15;
                size_t addr = ((((size_t)((b << 4) + h) * 128 + kt) * 4 + (ct >> 1)) * 4 + qv) * 128
                              + lv * 8 + (ct & 1) * 4;
                ushort4 o;
                o.x = f2bf(acc[i][j][0] + bn);
                o.y = f2bf(acc[i][j][1] + bn);
                o.z = f2bf(acc[i][j][2] + bn);
                o.w = f2bf(acc[i][j][3] + bn);
                *(ushort4*)&C[addr] = o;
            } else {
#pragma unroll
                for (int reg = 0; reg < 4; ++reg) {
                    int m = mb + reg;
                    float v = acc[i][j][reg] + bn;
                    if (MODE == 0) {
                        Cf[(size_t)m * HID + n] = v;
                    } else {
                        int b = m >> 11, s = m & 2047, h = n >> 7, d = n & 127;
                        if (zz == 1) {
                            // K-pack: key=s -> (kt, lk); d -> (kk, qk, e)
                            int kt = s >> 4, lk = s & 15, kk = d >> 5, qk = (d >> 3) & 3, e = d & 7;
                            size_t addr = ((((size_t)((b << 4) + h) * 128 + kt) * 4 + kk) * 4 + qk) * 128
                                          + lk * 8 + e;
                            C[addr] = f2bf(v);
                        } else {
                            C[(size_t)(((b << 4) + h) * S_LEN + s) * HDIM + d] = f2bf(v);
                        }
                    }
                }
            }
        }
    }
}

// ---------------------------------------------------------------- flash attention (R9)
// Grid: 1024 blocks; XCD-remapped so each XCD owns 4 consecutive bh (K/V 4MB ~ L2).
// 4 independent waves; strips {2j,2j+1,126-2j,127-2j}, role rotated per block so
// each SIMD gets a mix of strip lengths. Zero LDS / zero barriers.
// K tile double-buffered in regs (prefetch kt+1 during kt); V issued at top of
// iteration (consumed after QK+exp). All K/V loads are 16B, coalesced.
__launch_bounds__(256, 4)
__global__ void attn_kernel(const unsigned short* __restrict__ Qg,
                            const unsigned short* __restrict__ Kp,
                            const unsigned short* __restrict__ Vp,
                            unsigned short* __restrict__ O) {
    // XCD-aware remap: HW round-robins linear block id over 8 XCDs.
    int linear = blockIdx.y * 32 + blockIdx.x;   // 0..1023
    int xcd = linear & 7;
    int u = linear >> 3;                          // 0..127
    int bh = xcd * 4 + (u & 3);                   // 4 bh per XCD
    int j = u >> 2;                               // 0..31
    int b = bh >> 4, h = bh & 15;

    int tid = threadIdx.x, lane = tid & 63, w = tid >> 6;
    int l15 = lane & 15, quad = lane >> 4;

    int role = (w + (u >> 5)) & 3;                // per-CU-varying rotation
    int strip = (role < 2) ? (2 * j + role) : (126 - 2 * j + (role - 2));
    int r0 = strip * 16;

    const unsigned short* Qb = Qg + (size_t)bh * (S_LEN * HDIM);
    const unsigned short* Kb = Kp + (size_t)bh * 262144 + quad * 128 + l15 * 8;
    const unsigned short* Vb = Vp + (size_t)bh * 262144 + quad * 128 + l15 * 8;

    // Q as B-operand of S^T: B[n=qrow=l15][k=d=quad*8+..]
    bf16x8 qf[4];
#pragma unroll
    for (int kk = 0; kk < 4; ++kk)
        qf[kk] = *(const bf16x8*)&Qb[(size_t)(r0 + l15) * HDIM + kk * 32 + quad * 8];

    f32x4 o_acc[8];
#pragma unroll
    for (int c = 0; c < 8; ++c) o_acc[c] = (f32x4){0.f, 0.f, 0.f, 0.f};
    float l_part = 0.f;   // partial normalizer for qrow = r0 + l15

    const float k2 = 0.08838834764831845f * 1.4426950408889634f;  // scale*log2(e)

    int nkt = strip + 1;                  // 16-key tiles; last is the diagonal

    bf16x8 kA[4], kB[4], v[4];

#define LOADK(dst, t) do { size_t _o = (size_t)(t) * 2048;                         \
    dst[0] = *(const bf16x8*)&Kb[_o];                                              \
    dst[1] = *(const bf16x8*)&Kb[_o + 512];                                        \
    dst[2] = *(const bf16x8*)&Kb[_o + 1024];                                       \
    dst[3] = *(const bf16x8*)&Kb[_o + 1536]; } while (0)

#define LOADV(dst, t) do { size_t _o = (size_t)(t) * 2048;                         \
    dst[0] = *(const bf16x8*)&Vb[_o];                                              \
    dst[1] = *(const bf16x8*)&Vb[_o + 512];                                        \
    dst[2] = *(const bf16x8*)&Vb[_o + 1024];                                       \
    dst[3] = *(const bf16x8*)&Vb[_o + 1536]; } while (0)

#define VLO(x) __builtin_shufflevector(x, x, 0, 1, 2, 3)
#define VHI(x) __builtin_shufflevector(x, x, 4, 5, 6, 7)

    // One tile: S^T = K*Q^T (A=K-frag m=key, B=Q-frag n=qrow), p=exp2, O += P*V.
    // lane reg r holds S[qrow=r0+l15][key=t*16+quad*4+r]; P is directly the
    // A-fragment of 16x16x16 (A[m=l15][k=quad*4+r]).
#define TILE(kreg, t) do {                                                         \
    f32x4 st0 = (f32x4){0.f, 0.f, 0.f, 0.f};                                       \
    f32x4 st1 = (f32x4){0.f, 0.f, 0.f, 0.f};                                       \
    st0 = __builtin_amdgcn_mfma_f32_16x16x32_bf16(kreg[0], qf[0], st0, 0, 0, 0);   \
    st1 = __builtin_amdgcn_mfma_f32_16x16x32_bf16(kreg[1], qf[1], st1, 0, 0, 0);   \
    st0 = __builtin_amdgcn_mfma_f32_16x16x32_bf16(kreg[2], qf[2], st0, 0, 0, 0);   \
    st1 = __builtin_amdgcn_mfma_f32_16x16x32_bf16(kreg[3], qf[3], st1, 0, 0, 0);   \
    f32x4 stv = st0 + st1;                                                         \
    float p0, p1, p2, p3;                                                          \
    if ((t) == nkt - 1) {                                                          \
        p0 = (quad * 4 + 0 <= l15) ? exp2f(stv[0] * k2) : 0.f;                     \
        p1 = (quad * 4 + 1 <= l15) ? exp2f(stv[1] * k2) : 0.f;                     \
        p2 = (quad * 4 + 2 <= l15) ? exp2f(stv[2] * k2) : 0.f;                     \
        p3 = (quad * 4 + 3 <= l15) ? exp2f(stv[3] * k2) : 0.f;                     \
    } else {                                                                       \
        p0 = exp2f(stv[0] * k2); p1 = exp2f(stv[1] * k2);                          \
        p2 = exp2f(stv[2] * k2); p3 = exp2f(stv[3] * k2);                          \
    }                                                                              \
    l_part += (p0 + p1) + (p2 + p3);                                               \
    bf16x4 pf;                                                                     \
    pf[0] = (short)f2bf(p0); pf[1] = (short)f2bf(p1);                              \
    pf[2] = (short)f2bf(p2); pf[3] = (short)f2bf(p3);                              \
    o_acc[0] = pv_mfma(pf, VLO(v[0]), o_acc[0]);                                   \
    o_acc[1] = pv_mfma(pf, VHI(v[0]), o_acc[1]);                                   \
    o_acc[2] = pv_mfma(pf, VLO(v[1]), o_acc[2]);                                   \
    o_acc[3] = pv_mfma(pf, VHI(v[1]), o_acc[3]);                                   \
    o_acc[4] = pv_mfma(pf, VLO(v[2]), o_acc[4]);                                   \
    o_acc[5] = pv_mfma(pf, VHI(v[2]), o_acc[5]);                                   \
    o_acc[6] = pv_mfma(pf, VLO(v[3]), o_acc[6]);                                   \
    o_acc[7] = pv_mfma(pf, VHI(v[3]), o_acc[7]);                                   \
} while (0)

    LOADK(kA, 0);
    int kt = 0;
    while (true) {
        int ktn = (kt + 1 < nkt) ? kt + 1 : kt;      // uniform clamp, no branch
        LOADV(v, kt);
        LOADK(kB, ktn);
        TILE(kA, kt);
        if (++kt >= nkt) break;

        ktn = (kt + 1 < nkt) ? kt + 1 : kt;
        LOADV(v, kt);
        LOADK(kA, ktn);
        TILE(kB, kt);
        if (++kt >= nkt) break;
    }

#undef TILE
#undef LOADK
#undef LOADV
#undef VLO
#undef VHI

    // ---- normalizer: reduce over quads (lanes sharing l15)
    l_part += __shfl_xor(l_part, 16, 64);
    l_part += __shfl_xor(l_part, 32, 64);
    // l_part = l(qrow=r0+l15), uniform across quads

    // ---- epilogue: O[qrow=r0+quad*4+reg][d=ct*16+l15] / l -> bf16 [B][S][H]
#pragma unroll
    for (int reg = 0; reg < 4; ++reg) {
        float l = __shfl(l_part, quad * 4 + reg, 64);
        float inv = 1.f / l;
        int srow = r0 + quad * 4 + reg;
        unsigned short* op = O + (size_t)(b * S_LEN + srow) * HID + h * HDIM;
#pragma unroll
        for (int ct = 0; ct < 8; ++ct)
            op[ct * 16 + l15] = f2bf(o_acc[ct][reg] * inv);
    }
}

// ---------------------------------------------------------------- launch
extern "C" void kernel_launch(void* const* d_in, const int* in_sizes, int n_in,
                              void* d_out, int out_size, void* d_ws, size_t ws_size,
                              hipStream_t stream) {
    (void)in_sizes; (void)n_in; (void)out_size; (void)ws_size;
    const float* x  = (const float*)d_in[0];
    const float* wq = (const float*)d_in[2];
    const float* bq = (const float*)d_in[3];
    const float* wk = (const float*)d_in[4];
    const float* bk = (const float*)d_in[5];
    const float* wv = (const float*)d_in[6];
    const float* bv = (const float*)d_in[7];
    const float* wo = (const float*)d_in[8];
    const float* bo = (const float*)d_in[9];
    float* out = (float*)d_out;

    unsigned short* ws = (unsigned short*)d_ws;
    const size_t WSZ = 4194304;
    unsigned short* wqT = ws;                // [0, 4M)
    unsigned short* wkT = ws + WSZ;          // [4M, 8M)
    unsigned short* wvT = ws + 2 * WSZ;      // [8M, 12M)
    unsigned short* woT = ws + 3 * WSZ;      // [12M, 16M)
    unsigned short* xb  = ws + 4 * WSZ;      // [16M, 24M)
    unsigned short* Ab  = ws + 4 * WSZ;      // aliases xb (dead after QKV gemm)
    unsigned short* Qb  = ws + 6 * WSZ;      // [24M, 32M)
    unsigned short* Kb  = ws + 8 * WSZ;      // [32M, 40M)  fragment-packed
    unsigned short* Vb  = ws + 10 * WSZ;     // [40M, 48M)  fragment-packed

    convert_x<<<dim3(8192), 256, 0, stream>>>(x, xb);
    convert_wt<<<dim3(32, 32, 4), 256, 0, stream>>>(wq, wk, wv, wo, wqT, wkT, wvT, woT);
    gemm_bt<1><<<dim3(16, 32, 3), 256, 0, stream>>>(xb, wqT, wkT, wvT, bq, bk, bv,
                                                    Qb, Kb, Vb, nullptr);
    attn_kernel<<<dim3(32, 32), 256, 0, stream>>>(Qb, Kb, Vb, Ab);
    gemm_bt<0><<<dim3(16, 32, 1), 256, 0, stream>>>(Ab, woT, nullptr, nullptr,
                                                    bo, nullptr, nullptr,
                                                    nullptr, nullptr, nullptr, out);
}

// Round 2
// 408.865 us; speedup vs baseline: 1.3674x; 1.0392x over previous
//
#include <hip/hip_runtime.h>

// CausalSelfAttention: B=2, S=2048, H=2048, NH=16, HD=128. f32 in/out, bf16 MFMA inside.
// R10 = R9 + 8-phase-style GEMM (T2+T3+T4+T5). gemm_bt (m97 2-barrier structure,
// 715 TF, MfmaUtil 31%) replaced by gemm8:
//   BM=128 BN=256 BK=64, 512 thr (8 waves 2x4), per-wave 64x64 (acc[4][4], same
//   epilogue geometry as R9 -> pack formulas reused verbatim).
//   Per K-tile: 2 phases {ds_read x8 -> barrier -> lgkmcnt(0) -> setprio(1)+16 MFMA}.
//   Stage of tile t+2 issued mid-tile after a barrier certifies all reads of the
//   current buf; single s_waitcnt vmcnt(6) per tile (6 loads in flight across
//   every barrier, issued ~1.5 tiles before use). Raw s_barrier + asm memory
//   fences (NOT __syncthreads -> would drain vmcnt).
//   T2: LDS 16B-slot XOR swizzle (slot ^= row&7), applied as pre-swizzled global
//   source for global_load_lds (linear dest, rule #21) + swizzled ds_read.
//   T1: QKV fused N=6144 -> 768 blocks = 3x256 exact; out-proj 256 blocks exact;
//   per-XCD clustering = 3 (resp 1) B-panel columns -> 3MB L2-resident weights.
// attn_kernel / converts unchanged from R9 (verified).

using bf16x8 = __attribute__((ext_vector_type(8))) short;
using bf16x4 = __attribute__((ext_vector_type(4))) short;
using f32x4  = __attribute__((ext_vector_type(4))) float;

#define S_LEN 2048
#define NHEAD 16
#define HDIM  128
#define HID   2048

__device__ __forceinline__ unsigned short f2bf(float f) {
    unsigned int u = __float_as_uint(f);
    u += 0x7fffu + ((u >> 16) & 1u);   // round-to-nearest-even
    return (unsigned short)(u >> 16);
}
__device__ __forceinline__ void gl2lds16(const void* g, void* l) {
    __builtin_amdgcn_global_load_lds(
        (const __attribute__((address_space(1))) void*)g,
        (__attribute__((address_space(3))) void*)l, 16, 0, 0);
}

// 16x16x16 bf16 MFMA, device-guarded (host pass must not reference the builtin).
__device__ __forceinline__ f32x4 pv_mfma(bf16x4 a, bf16x4 b, f32x4 c) {
#if defined(__HIP_DEVICE_COMPILE__)
#if __has_builtin(__builtin_amdgcn_mfma_f32_16x16x16bf16_1k)
    return __builtin_amdgcn_mfma_f32_16x16x16bf16_1k(a, b, c, 0, 0, 0);
#else
    asm("v_mfma_f32_16x16x16_bf16 %0, %1, %2, %0" : "+v"(c) : "v"(a), "v"(b));
    return c;
#endif
#else
    (void)a; (void)b;
    return c;
#endif
}

// ---------------------------------------------------------------- convert x: f32 -> bf16
__global__ void convert_x(const float* __restrict__ x, unsigned short* __restrict__ xb) {
    int i = (blockIdx.x * 256 + threadIdx.x) * 4;
    float4 v = *(const float4*)(x + i);
    ushort4 o;
    o.x = f2bf(v.x); o.y = f2bf(v.y); o.z = f2bf(v.z); o.w = f2bf(v.w);
    *(ushort4*)(xb + i) = o;
}

// ------------------------------------------------- convert+transpose weights: f32 -> bf16^T
__global__ void convert_wt(const float* __restrict__ w0, const float* __restrict__ w1,
                           const float* __restrict__ w2, const float* __restrict__ w3,
                           unsigned short* __restrict__ t0, unsigned short* __restrict__ t1,
                           unsigned short* __restrict__ t2, unsigned short* __restrict__ t3) {
    __shared__ float tile[64][65];
    int z = blockIdx.z;
    const float* src = (z == 0) ? w0 : (z == 1) ? w1 : (z == 2) ? w2 : w3;
    unsigned short* dst = (z == 0) ? t0 : (z == 1) ? t1 : (z == 2) ? t2 : t3;
    int r0 = blockIdx.y * 64, c0 = blockIdx.x * 64;
    int t = threadIdx.x;
    for (int i = t; i < 64 * 64; i += 256) {
        int r = i >> 6, c = i & 63;
        tile[r][c] = src[(size_t)(r0 + r) * HID + c0 + c];
    }
    __syncthreads();
    for (int i = t; i < 64 * 64; i += 256) {
        int r = i & 63, c = i >> 6;
        dst[(size_t)(c0 + c) * HID + r0 + r] = f2bf(tile[r][c]);
    }
}

// ---------------------------------------------------------------- GEMM, pipelined (R10)
// C[4096][N] = A @ Bt^T + bias; A,Bt bf16, fp32 acc.
// MODE 0: N=2048, f32 row-major to Cf (out-proj). Grid 256.
// MODE 1: N=6144 fused QKV (z = ncol>>11). Grid 768.
//         z=0 (Q): bf16 head-split [b,h,s,d]
//         z=1 (K): fragment-packed Kp[bh][kt16][kk4][quad][l15][8]
//         z=2 (V): fragment-packed Vp[bh][kt16][ctp4][qv4][lv16][8]
template <int MODE>
__launch_bounds__(512, 2)
__global__ void gemm8(const unsigned short* __restrict__ A,
                      const unsigned short* __restrict__ Bt0,
                      const unsigned short* __restrict__ Bt1,
                      const unsigned short* __restrict__ Bt2,
                      const float* __restrict__ bias0,
                      const float* __restrict__ bias1,
                      const float* __restrict__ bias2,
                      unsigned short* __restrict__ C0,
                      unsigned short* __restrict__ C1,
                      unsigned short* __restrict__ C2,
                      float* __restrict__ Cf) {
    // LDS: A-tile 128x64 bf16 (16KB) x2buf, B-tile 256x64 (32KB) x2buf = 96KB.
    __shared__ __align__(16) unsigned short lds[49152];
    unsigned short* const A0 = lds;            // elems [0, 8192)
    unsigned short* const A1 = lds + 8192;
    unsigned short* const B0 = lds + 16384;    // elems [16384, 32768)
    unsigned short* const B1 = lds + 32768;

    // XCD clustering: HW round-robins linear id %8; give each XCD contiguous
    // columns of the C-tile grid (32 m-tiles per column).
    const int CPX = (MODE == 1) ? 96 : 32;     // blocks per XCD
    int vb = (blockIdx.x & 7) * CPX + (blockIdx.x >> 3);
    int m0  = (vb & 31) * 128;
    int n0g = (vb >> 5) * 256;                 // global col (0..6143 fused)

    const unsigned short* Bt = Bt0;
    const float* bias = bias0;
    unsigned short* C = C0;
    int z = 0;
    if (MODE == 1) {
        z = n0g >> 11;
        if (z == 1) { Bt = Bt1; bias = bias1; C = C1; }
        else if (z == 2) { Bt = Bt2; bias = bias2; C = C2; }
    }
    int nb0 = n0g & 2047;                      // col within the z-matrix

    int tid = threadIdx.x;
    int lane = tid & 63;
    int wv_ = tid >> 6;
    int wr = wv_ >> 2, wc = wv_ & 3;           // 2x4 wave grid; wave tile 64x64
    int l15 = lane & 15, quad = lane >> 4;

    // ---- staging: 512 thr x 16B = 8KB/issue = 64 rows. T2 pre-swizzled source:
    // LDS slot s (linear dest, forced by gl2lds) receives global col (s ^ row&7).
    int tr = tid >> 3;                          // row within 64-row sweep
    int tc = ((tid & 7) ^ (tr & 7)) << 3;       // swizzled col (elems)
    const unsigned short* gA = A  + (size_t)(m0  + tr) * HID + tc;
    const unsigned short* gB = Bt + (size_t)(nb0 + tr) * HID + tc;
    const int td8 = tid * 8;                    // LDS dest elem offset (= tid*16B)

    // ---- fragment ds_read offsets (elems). Read swizzle = store swizzle.
    int arow = (wr * 64 + l15) * 64;
    int brow = (wc * 64 + l15) * 64;
    int sw0 = ((quad ^ (l15 & 7)) << 3);        // kk=0: slot kk*4+quad, XOR row&7
    int sw1 = (((4 + quad) ^ (l15 & 7)) << 3);  // kk=1

    f32x4 acc[4][4];
#pragma unroll
    for (int i = 0; i < 4; ++i)
#pragma unroll
        for (int j = 0; j < 4; ++j) acc[i][j] = (f32x4){0.f, 0.f, 0.f, 0.f};

#define STAGE8(kt, AD, BD) do { int _kc = (kt) * 64;                        \
    gl2lds16(gA + _kc,              (AD) + td8);                            \
    gl2lds16(gA + 64 * HID + _kc,   (AD) + 4096 + td8);                     \
    gl2lds16(gB + _kc,              (BD) + td8);                            \
    gl2lds16(gB + 64 * HID + _kc,   (BD) + 4096 + td8);                     \
    gl2lds16(gB + 128 * HID + _kc,  (BD) + 8192 + td8);                     \
    gl2lds16(gB + 192 * HID + _kc,  (BD) + 12288 + td8); } while (0)

#define FENCE() asm volatile("" ::: "memory")
#define BAR()   do { FENCE(); __builtin_amdgcn_s_barrier(); FENCE(); } while (0)
#define WAIT_LGKM0() do { asm volatile("s_waitcnt lgkmcnt(0)" ::: "memory");      \
                          __builtin_amdgcn_sched_barrier(0); } while (0)
#define WAIT_VM6()   do { asm volatile("s_waitcnt vmcnt(6)" ::: "memory");        \
                          __builtin_amdgcn_sched_barrier(0); } while (0)

    auto ktile = [&](unsigned short* AD, unsigned short* BD, int ks) {
        // ---- phase A (kk0): 8 ds_read_b128 -> barrier -> lgkm0 -> 16 MFMA
        {
            bf16x8 av[4], bv[4];
            av[0] = *(const bf16x8*)(AD + arow + sw0);
            av[1] = *(const bf16x8*)(AD + arow + 1024 + sw0);
            av[2] = *(const bf16x8*)(AD + arow + 2048 + sw0);
            av[3] = *(const bf16x8*)(AD + arow + 3072 + sw0);
            bv[0] = *(const bf16x8*)(BD + brow + sw0);
            bv[1] = *(const bf16x8*)(BD + brow + 1024 + sw0);
            bv[2] = *(const bf16x8*)(BD + brow + 2048 + sw0);
            bv[3] = *(const bf16x8*)(BD + brow + 3072 + sw0);
            BAR();
            WAIT_LGKM0();
            __builtin_amdgcn_s_setprio(1);
#pragma unroll
            for (int mi = 0; mi < 4; ++mi)
#pragma unroll
                for (int jj = 0; jj < 4; ++jj)
                    acc[mi][jj] = __builtin_amdgcn_mfma_f32_16x16x32_bf16(av[mi], bv[jj], acc[mi][jj], 0, 0, 0);
            __builtin_amdgcn_s_setprio(0);
            BAR();
        }
        // ---- phase B (kk1): reads -> lgkm0 -> barrier (all waves' reads done)
        //      -> stage tile t+2 into THIS buf -> 16 MFMA -> vmcnt(6) -> barrier
        {
            bf16x8 av[4], bv[4];
            av[0] = *(const bf16x8*)(AD + arow + sw1);
            av[1] = *(const bf16x8*)(AD + arow + 1024 + sw1);
            av[2] = *(const bf16x8*)(AD + arow + 2048 + sw1);
            av[3] = *(const bf16x8*)(AD + arow + 3072 + sw1);
            bv[0] = *(const bf16x8*)(BD + brow + sw1);
            bv[1] = *(const bf16x8*)(BD + brow + 1024 + sw1);
            bv[2] = *(const bf16x8*)(BD + brow + 2048 + sw1);
            bv[3] = *(const bf16x8*)(BD + brow + 3072 + sw1);
            WAIT_LGKM0();
            BAR();
            STAGE8(ks, AD, BD);
            __builtin_amdgcn_s_setprio(1);
#pragma unroll
            for (int mi = 0; mi < 4; ++mi)
#pragma unroll
                for (int jj = 0; jj < 4; ++jj)
                    acc[mi][jj] = __builtin_amdgcn_mfma_f32_16x16x32_bf16(av[mi], bv[jj], acc[mi][jj], 0, 0, 0);
            __builtin_amdgcn_s_setprio(0);
            WAIT_VM6();
            BAR();
        }
    };

    // prologue: tile0 -> buf0, tile1 -> buf1; wait tile0 landed (6 newest stay in flight)
    STAGE8(0, A0, B0);
    STAGE8(1, A1, B1);
    WAIT_VM6();
    BAR();

    for (int t = 0; t < 32; t += 2) {
        ktile(A0, B0, (t + 2 < 32) ? t + 2 : 31);
        ktile(A1, B1, (t + 3 < 32) ? t + 3 : 31);
    }
    asm volatile("s_waitcnt vmcnt(0)" ::: "memory");   // drain stray stages

#undef STAGE8
#undef FENCE
#undef BAR
#undef WAIT_LGKM0
#undef WAIT_VM6

    // ---- epilogue (same per-wave geometry as R9; pack formulas verbatim)
#pragma unroll
    for (int j = 0; j < 4; ++j) {
        int n = nb0 + wc * 64 + j * 16 + l15;
        float bn = bias[n];
#pragma unroll
        for (int i = 0; i < 4; ++i) {
            int mb = m0 + wr * 64 + i * 16 + quad * 4;   // base row, regs = mb..mb+3
            if (MODE == 1 && z == 2) {
                // V-pack: 4 regs = 4 consecutive keys (e=0..3) -> one ushort4.
                int b = mb >> 11, s = mb & 2047, h = n >> 7, d = n & 127;
                int kt = s >> 4, qv = (s >> 2) & 3, ct = d >> 4, lv = d & 15;
                size_t addr = ((((size_t)((b << 4) + h) * 128 + kt) * 4 + (ct >> 1)) * 4 + qv) * 128
                              + lv * 8 + (ct & 1) * 4;
                ushort4 o;
                o.x = f2bf(acc[i][j][0] + bn);
                o.y = f2bf(acc[i][j][1] + bn);
                o.z = f2bf(acc[i][j][2] + bn);
                o.w = f2bf(acc[i][j][3] + bn);
                *(ushort4*)&C[addr] = o;
            } else {
#pragma unroll
                for (int reg = 0; reg < 4; ++reg) {
                    int m = mb + reg;
                    float v = acc[i][j][reg] + bn;
                    if (MODE == 0) {
                        Cf[(size_t)m * HID + n] = v;
                    } else {
                        int b = m >> 11, s = m & 2047, h = n >> 7, d = n & 127;
                        if (z == 1) {
                            // K-pack: key=s -> (kt, lk); d -> (kk, qk, e)
                            int kt = s >> 4, lk = s & 15, kk = d >> 5, qk = (d >> 3) & 3, e = d & 7;
                            size_t addr = ((((size_t)((b << 4) + h) * 128 + kt) * 4 + kk) * 4 + qk) * 128
                                          + lk * 8 + e;
                            C[addr] = f2bf(v);
                        } else {
                            C[(size_t)(((b << 4) + h) * S_LEN + s) * HDIM + d] = f2bf(v);
                        }
                    }
                }
            }
        }
    }
}

// ---------------------------------------------------------------- flash attention (R9, unchanged)
__launch_bounds__(256, 4)
__global__ void attn_kernel(const unsigned short* __restrict__ Qg,
                            const unsigned short* __restrict__ Kp,
                            const unsigned short* __restrict__ Vp,
                            unsigned short* __restrict__ O) {
    int linear = blockIdx.y * 32 + blockIdx.x;   // 0..1023
    int xcd = linear & 7;
    int u = linear >> 3;                          // 0..127
    int bh = xcd * 4 + (u & 3);                   // 4 bh per XCD
    int j = u >> 2;                               // 0..31
    int b = bh >> 4, h = bh & 15;

    int tid = threadIdx.x, lane = tid & 63, w = tid >> 6;
    int l15 = lane & 15, quad = lane >> 4;

    int role = (w + (u >> 5)) & 3;                // per-CU-varying rotation
    int strip = (role < 2) ? (2 * j + role) : (126 - 2 * j + (role - 2));
    int r0 = strip * 16;

    const unsigned short* Qb = Qg + (size_t)bh * (S_LEN * HDIM);
    const unsigned short* Kb = Kp + (size_t)bh * 262144 + quad * 128 + l15 * 8;
    const unsigned short* Vb = Vp + (size_t)bh * 262144 + quad * 128 + l15 * 8;

    bf16x8 qf[4];
#pragma unroll
    for (int kk = 0; kk < 4; ++kk)
        qf[kk] = *(const bf16x8*)&Qb[(size_t)(r0 + l15) * HDIM + kk * 32 + quad * 8];

    f32x4 o_acc[8];
#pragma unroll
    for (int c = 0; c < 8; ++c) o_acc[c] = (f32x4){0.f, 0.f, 0.f, 0.f};
    float l_part = 0.f;

    const float k2 = 0.08838834764831845f * 1.4426950408889634f;  // scale*log2(e)

    int nkt = strip + 1;

    bf16x8 kA[4], kB[4], v[4];

#define LOADK(dst, t) do { size_t _o = (size_t)(t) * 2048;                         \
    dst[0] = *(const bf16x8*)&Kb[_o];                                              \
    dst[1] = *(const bf16x8*)&Kb[_o + 512];                                        \
    dst[2] = *(const bf16x8*)&Kb[_o + 1024];                                       \
    dst[3] = *(const bf16x8*)&Kb[_o + 1536]; } while (0)

#define LOADV(dst, t) do { size_t _o = (size_t)(t) * 2048;                         \
    dst[0] = *(const bf16x8*)&Vb[_o];                                              \
    dst[1] = *(const bf16x8*)&Vb[_o + 512];                                        \
    dst[2] = *(const bf16x8*)&Vb[_o + 1024];                                       \
    dst[3] = *(const bf16x8*)&Vb[_o + 1536]; } while (0)

#define VLO(x) __builtin_shufflevector(x, x, 0, 1, 2, 3)
#define VHI(x) __builtin_shufflevector(x, x, 4, 5, 6, 7)

#define TILE(kreg, t) do {                                                         \
    f32x4 st0 = (f32x4){0.f, 0.f, 0.f, 0.f};                                       \
    f32x4 st1 = (f32x4){0.f, 0.f, 0.f, 0.f};                                       \
    st0 = __builtin_amdgcn_mfma_f32_16x16x32_bf16(kreg[0], qf[0], st0, 0, 0, 0);   \
    st1 = __builtin_amdgcn_mfma_f32_16x16x32_bf16(kreg[1], qf[1], st1, 0, 0, 0);   \
    st0 = __builtin_amdgcn_mfma_f32_16x16x32_bf16(kreg[2], qf[2], st0, 0, 0, 0);   \
    st1 = __builtin_amdgcn_mfma_f32_16x16x32_bf16(kreg[3], qf[3], st1, 0, 0, 0);   \
    f32x4 stv = st0 + st1;                                                         \
    float p0, p1, p2, p3;                                                          \
    if ((t) == nkt - 1) {                                                          \
        p0 = (quad * 4 + 0 <= l15) ? exp2f(stv[0] * k2) : 0.f;                     \
        p1 = (quad * 4 + 1 <= l15) ? exp2f(stv[1] * k2) : 0.f;                     \
        p2 = (quad * 4 + 2 <= l15) ? exp2f(stv[2] * k2) : 0.f;                     \
        p3 = (quad * 4 + 3 <= l15) ? exp2f(stv[3] * k2) : 0.f;                     \
    } else {                                                                       \
        p0 = exp2f(stv[0] * k2); p1 = exp2f(stv[1] * k2);                          \
        p2 = exp2f(stv[2] * k2); p3 = exp2f(stv[3] * k2);                          \
    }                                                                              \
    l_part += (p0 + p1) + (p2 + p3);                                               \
    bf16x4 pf;                                                                     \
    pf[0] = (short)f2bf(p0); pf[1] = (short)f2bf(p1);                              \
    pf[2] = (short)f2bf(p2); pf[3] = (short)f2bf(p3);                              \
    o_acc[0] = pv_mfma(pf, VLO(v[0]), o_acc[0]);                                   \
    o_acc[1] = pv_mfma(pf, VHI(v[0]), o_acc[1]);                                   \
    o_acc[2] = pv_mfma(pf, VLO(v[1]), o_acc[2]);                                   \
    o_acc[3] = pv_mfma(pf, VHI(v[1]), o_acc[3]);                                   \
    o_acc[4] = pv_mfma(pf, VLO(v[2]), o_acc[4]);                                   \
    o_acc[5] = pv_mfma(pf, VHI(v[2]), o_acc[5]);                                   \
    o_acc[6] = pv_mfma(pf, VLO(v[3]), o_acc[6]);                                   \
    o_acc[7] = pv_mfma(pf, VHI(v[3]), o_acc[7]);                                   \
} while (0)

    LOADK(kA, 0);
    int kt = 0;
    while (true) {
        int ktn = (kt + 1 < nkt) ? kt + 1 : kt;
        LOADV(v, kt);
        LOADK(kB, ktn);
        TILE(kA, kt);
        if (++kt >= nkt) break;

        ktn = (kt + 1 < nkt) ? kt + 1 : kt;
        LOADV(v, kt);
        LOADK(kA, ktn);
        TILE(kB, kt);
        if (++kt >= nkt) break;
    }

#undef TILE
#undef LOADK
#undef LOADV
#undef VLO
#undef VHI

    l_part += __shfl_xor(l_part, 16, 64);
    l_part += __shfl_xor(l_part, 32, 64);

#pragma unroll
    for (int reg = 0; reg < 4; ++reg) {
        float l = __shfl(l_part, quad * 4 + reg, 64);
        float inv = 1.f / l;
        int srow = r0 + quad * 4 + reg;
        unsigned short* op = O + (size_t)(b * S_LEN + srow) * HID + h * HDIM;
#pragma unroll
        for (int ct = 0; ct < 8; ++ct)
            op[ct * 16 + l15] = f2bf(o_acc[ct][reg] * inv);
    }
}

// ---------------------------------------------------------------- launch
extern "C" void kernel_launch(void* const* d_in, const int* in_sizes, int n_in,
                              void* d_out, int out_size, void* d_ws, size_t ws_size,
                              hipStream_t stream) {
    (void)in_sizes; (void)n_in; (void)out_size; (void)ws_size;
    const float* x  = (const float*)d_in[0];
    const float* wq = (const float*)d_in[2];
    const float* bq = (const float*)d_in[3];
    const float* wk = (const float*)d_in[4];
    const float* bk = (const float*)d_in[5];
    const float* wv = (const float*)d_in[6];
    const float* bv = (const float*)d_in[7];
    const float* wo = (const float*)d_in[8];
    const float* bo = (const float*)d_in[9];
    float* out = (float*)d_out;

    unsigned short* ws = (unsigned short*)d_ws;
    const size_t WSZ = 4194304;
    unsigned short* wqT = ws;                // [0, 4M)
    unsigned short* wkT = ws + WSZ;          // [4M, 8M)
    unsigned short* wvT = ws + 2 * WSZ;      // [8M, 12M)
    unsigned short* woT = ws + 3 * WSZ;      // [12M, 16M)
    unsigned short* xb  = ws + 4 * WSZ;      // [16M, 24M)
    unsigned short* Ab  = ws + 4 * WSZ;      // aliases xb (dead after QKV gemm)
    unsigned short* Qb  = ws + 6 * WSZ;      // [24M, 32M)
    unsigned short* Kb  = ws + 8 * WSZ;      // [32M, 40M)  fragment-packed
    unsigned short* Vb  = ws + 10 * WSZ;     // [40M, 48M)  fragment-packed

    convert_x<<<dim3(8192), 256, 0, stream>>>(x, xb);
    convert_wt<<<dim3(32, 32, 4), 256, 0, stream>>>(wq, wk, wv, wo, wqT, wkT, wvT, woT);
    gemm8<1><<<dim3(768), 512, 0, stream>>>(xb, wqT, wkT, wvT, bq, bk, bv,
                                            Qb, Kb, Vb, nullptr);
    attn_kernel<<<dim3(32, 32), 256, 0, stream>>>(Qb, Kb, Vb, Ab);
    gemm8<0><<<dim3(256), 512, 0, stream>>>(Ab, woT, nullptr, nullptr,
                                            bo, nullptr, nullptr,
                                            nullptr, nullptr, nullptr, out);
}